// Round 9
// baseline (2591.403 us; speedup 1.0000x reference)
//
#include <hip/hip_runtime.h>
#include <math.h>

typedef _Float16 half_t;
typedef _Float16 half4 __attribute__((ext_vector_type(4)));
typedef _Float16 half8 __attribute__((ext_vector_type(8)));
typedef short short8 __attribute__((ext_vector_type(8)));
typedef float f32x4 __attribute__((ext_vector_type(4)));
typedef unsigned short u16;
typedef unsigned short u16x4 __attribute__((ext_vector_type(4)));

#define L_SEQ 1536
#define GRAM_PLANE (64*1536)

// ---------- helpers ----------
__device__ __forceinline__ u16 f2bf(float f){
  unsigned u = __float_as_uint(f);
  return (u16)((u + 0x7FFFu + ((u>>16)&1u)) >> 16);
}
__device__ __forceinline__ float bf2f(u16 h){ return __uint_as_float(((unsigned)h)<<16); }
__device__ __forceinline__ float gelu_f(float x){ return 0.5f*x*(1.f+erff(x*0.70710678118f)); }

__device__ __forceinline__ void load_lds16(const void* g, void* l){
  __builtin_amdgcn_global_load_lds((const __attribute__((address_space(1))) void*)g,
                                   (__attribute__((address_space(3))) void*)l, 16, 0, 0);
}
__device__ __forceinline__ f32x4 mfma_bf(short8 a, short8 b, f32x4 c){
  return __builtin_amdgcn_mfma_f32_16x16x32_bf16(a,b,c,0,0,0);
}
__device__ __forceinline__ f32x4 mfma_fp(half8 a, half8 b, f32x4 c){
  return __builtin_amdgcn_mfma_f32_16x16x32_f16(a,b,c,0,0,0);
}

// store activation as bf16 hi/lo pair, row stride 512
__device__ __forceinline__ void store_pair(float v, size_t row, int d, u16* X2B){
  size_t r2 = row*512 + d;
  u16 hi = f2bf(v);
  X2B[r2] = hi;
  X2B[r2+256] = f2bf(v - bf2f(hi));
}

// ---------- weight prep ----------
// W [256,256] f32 slice -> W3 [256,768] bf16 = [Wh|Wh|Wl]  (K=768 fused hi/lo GEMM)
__global__ __launch_bounds__(256) void w4b768_k(const float* __restrict__ W, u16* __restrict__ W4, int n){
  int i = blockIdx.x*256 + threadIdx.x;
  if (i >= n) return;
  int ro = i >> 8, c = i & 255;
  float v = W[i];
  u16 hi = f2bf(v);
  u16 lo = f2bf(v - bf2f(hi));
  u16* r = W4 + (size_t)ro*768;
  r[c] = hi; r[c+256] = hi; r[c+512] = lo;
}
// Wv [256,256] -> padded rows of stride 768 (cols 0-255 valid)
__global__ __launch_bounds__(256) void wvpad_k(const float* __restrict__ W, u16* __restrict__ W4, int n){
  int i = blockIdx.x*256 + threadIdx.x;
  if (i >= n) return;
  W4[(size_t)(i>>8)*768 + (i&255)] = f2bf(W[i]);
}
__global__ __launch_bounds__(256) void castb_k(const float* __restrict__ W, u16* __restrict__ Wb, int n){
  for (int i = blockIdx.x*256 + threadIdx.x; i < n; i += gridDim.x*256)
    Wb[i] = f2bf(W[i]);
}

// ---------- embedding: circular conv1d k=3, 7->256; 64 tokens per block ----------
__global__ __launch_bounds__(256) void embed_k(const float* __restrict__ XE, const float* __restrict__ EW,
                                               u16* __restrict__ X2B){
  __shared__ float xs[66*7];
  int b = blockIdx.x / 24, lc = blockIdx.x % 24;
  int l0 = lc*64;
  int tid = threadIdx.x;
  for (int i = tid; i < 66*7; i += 256){
    int r = i/7, c = i%7;
    int g = l0 - 1 + r; if (g < 0) g += L_SEQ; if (g >= L_SEQ) g -= L_SEQ;
    xs[i] = XE[((size_t)b*L_SEQ + g)*7 + c];
  }
  __syncthreads();
  int d = tid;
  float wp[21];
  #pragma unroll
  for (int i=0;i<21;i++) wp[i] = EW[d*21+i];
  for (int j = 0; j < 64; j++){
    float acc = 0.f;
    #pragma unroll
    for (int c = 0; c < 7; c++)
      #pragma unroll
      for (int k = 0; k < 3; k++) acc += xs[(j+k)*7+c] * wp[c*3+k];
    store_pair(acc, (size_t)b*L_SEQ + l0 + j, d, X2B);
  }
}

// ---------- 128x128 MFMA bf16 GEMM: 2-phase prefetch, dbuf LDS, XOR-swizzled reads ----------
// bm = blockIdx.x (fastest), bn = blockIdx.y
// EPI: 0 = bf16 store, 1 = bf16 gelu store, 2 = f32 store + residual(pair)
template<int EPI, bool KMOD>
__global__ __launch_bounds__(256) void gemm_k(const u16* __restrict__ A, int lda,
                                              const u16* __restrict__ B, int ldb,
                                              const float* __restrict__ bias,
                                              void* __restrict__ C, int ldc,
                                              const u16* __restrict__ res,
                                              int K){
  __shared__ __align__(16) u16 As[2][128*32];
  __shared__ __align__(16) u16 Bs[2][128*32];
  const int tid = threadIdx.x;
  const int wv = tid>>6, ln = tid&63;
  const int lrow = ln&15, lk = ln>>4;
  const int bm = blockIdx.x, bn = blockIdx.y;
  const int wr = wv>>1, wc = wv&1;
  f32x4 acc[4][4];
  #pragma unroll
  for (int i=0;i<4;i++)
    #pragma unroll
    for (int j=0;j<4;j++) acc[i][j] = f32x4{0.f,0.f,0.f,0.f};

  const int nt = K >> 5;
  auto stage = [&](int buf, int t){
    int k0 = t*32;
    int ka = KMOD ? (k0 & 511) : k0;
    #pragma unroll
    for (int p=0;p<2;p++){
      int chunk = (wv*2+p)*64 + ln;
      int row = chunk>>2, c16 = chunk&3;
      int sw = (row>>1)&3;
      load_lds16(A + (size_t)(bm*128 + row)*lda + (ka + ((c16^sw)*8)), &As[buf][(size_t)chunk*8]);
      load_lds16(B + (size_t)(bn*128 + row)*ldb + (k0 + ((c16^sw)*8)), &Bs[buf][(size_t)chunk*8]);
    }
  };

  stage(0, 0);
  int cur = 0;
  const int swR = (lrow>>1)&3;
  for (int t = 0; t < nt; t++){
    __syncthreads();
    if (t+1 < nt) stage(cur^1, t+1);
    short8 av[4], bv[4];
    #pragma unroll
    for (int mi=0;mi<4;mi++) av[mi] = *(const short8*)&As[cur][(wr*64 + mi*16 + lrow)*32 + ((lk^swR)*8)];
    #pragma unroll
    for (int ni=0;ni<4;ni++) bv[ni] = *(const short8*)&Bs[cur][(wc*64 + ni*16 + lrow)*32 + ((lk^swR)*8)];
    #pragma unroll
    for (int mi=0;mi<4;mi++)
      #pragma unroll
      for (int ni=0;ni<4;ni++)
        acc[mi][ni] = mfma_bf(av[mi], bv[ni], acc[mi][ni]);
    cur ^= 1;
  }

  #pragma unroll
  for (int mi=0;mi<4;mi++){
    #pragma unroll
    for (int ni=0;ni<4;ni++){
      int col = bn*128 + wc*64 + ni*16 + lrow;
      float bs = bias[col];
      #pragma unroll
      for (int r=0;r<4;r++){
        int row = bm*128 + wr*64 + mi*16 + lk*4 + r;
        float v = acc[mi][ni][r] + bs;
        if (EPI==0){ ((u16*)C)[(size_t)row*ldc + col] = f2bf(v); }
        else if (EPI==1){ ((u16*)C)[(size_t)row*ldc + col] = f2bf(gelu_f(v)); }
        else {
          float rv = bf2f(res[(size_t)row*512 + col]) + bf2f(res[(size_t)row*512 + 256 + col]);
          ((float*)C)[(size_t)row*ldc + col] = v + rv;
        }
      }
    }
  }
}

// ---------- unified QKV projection GEMM ----------
// B layout per layer: rows 0-255 = Wq3 [Wh|Wh|Wl] (ldb 768), 256-511 = Wk3, 512-767 = Wv (cols 0-255)
// bn 0-1 -> Q (K=768, fp16 pair out), 2-3 -> K (K=768), 4-5 -> V (K=256, bf16 out ldc 256)
__global__ __launch_bounds__(256) void gemmqkv_k(const u16* __restrict__ A,
                                                 const u16* __restrict__ B,
                                                 const float* __restrict__ bq,
                                                 const float* __restrict__ bk,
                                                 const float* __restrict__ bv,
                                                 u16* __restrict__ Q2, u16* __restrict__ K2,
                                                 u16* __restrict__ V2){
  __shared__ __align__(16) u16 As[2][128*32];
  __shared__ __align__(16) u16 Bs[2][128*32];
  const int tid = threadIdx.x;
  const int wv = tid>>6, ln = tid&63;
  const int lrow = ln&15, lk = ln>>4;
  const int bm = blockIdx.x, bn = blockIdx.y;
  const int wr = wv>>1, wc = wv&1;
  const int nt = (bn < 4) ? 24 : 8;
  f32x4 acc[4][4];
  #pragma unroll
  for (int i=0;i<4;i++)
    #pragma unroll
    for (int j=0;j<4;j++) acc[i][j] = f32x4{0.f,0.f,0.f,0.f};

  auto stage = [&](int buf, int t){
    int k0 = t*32;
    int ka = k0 & 511;
    #pragma unroll
    for (int p=0;p<2;p++){
      int chunk = (wv*2+p)*64 + ln;
      int row = chunk>>2, c16 = chunk&3;
      int sw = (row>>1)&3;
      load_lds16(A + (size_t)(bm*128 + row)*512 + (ka + ((c16^sw)*8)), &As[buf][(size_t)chunk*8]);
      load_lds16(B + (size_t)(bn*128 + row)*768 + (k0 + ((c16^sw)*8)), &Bs[buf][(size_t)chunk*8]);
    }
  };

  stage(0, 0);
  int cur = 0;
  const int swR = (lrow>>1)&3;
  for (int t = 0; t < nt; t++){
    __syncthreads();
    if (t+1 < nt) stage(cur^1, t+1);
    short8 av[4], bv_[4];
    #pragma unroll
    for (int mi=0;mi<4;mi++) av[mi] = *(const short8*)&As[cur][(wr*64 + mi*16 + lrow)*32 + ((lk^swR)*8)];
    #pragma unroll
    for (int ni=0;ni<4;ni++) bv_[ni] = *(const short8*)&Bs[cur][(wc*64 + ni*16 + lrow)*32 + ((lk^swR)*8)];
    #pragma unroll
    for (int mi=0;mi<4;mi++)
      #pragma unroll
      for (int ni=0;ni<4;ni++)
        acc[mi][ni] = mfma_bf(av[mi], bv_[ni], acc[mi][ni]);
    cur ^= 1;
  }

  const int proj = bn>>1, half = bn&1;
  const float* bias = (proj==0) ? bq : (proj==1) ? bk : bv;
  #pragma unroll
  for (int mi=0;mi<4;mi++){
    #pragma unroll
    for (int ni=0;ni<4;ni++){
      int col = half*128 + wc*64 + ni*16 + lrow;
      float bs = bias[col];
      #pragma unroll
      for (int r=0;r<4;r++){
        int row = bm*128 + wr*64 + mi*16 + lk*4 + r;
        float v = acc[mi][ni][r] + bs;
        if (proj==2){
          V2[(size_t)row*256 + col] = f2bf(v);
        } else {
          half_t hi = (half_t)v;
          half_t* Cp = (half_t*)((proj==0) ? Q2 : K2);
          Cp[(size_t)row*512 + col] = hi;
          Cp[(size_t)row*512 + 256 + col] = (half_t)((v - (float)hi)*512.f);
        }
      }
    }
  }
}

// ---------- banded circular gram + diagonal reduce; jt-split x2, 2-phase prefetch + swizzle ----------
// id = low3(b) | 8*( half + 2*tb + 16*(b>>3) )
__global__ __launch_bounds__(256) void gram_k(const u16* __restrict__ Q2, const u16* __restrict__ K2,
                                              float* __restrict__ MCP){
  __shared__ __align__(16) union UN {
    struct { u16 As[2][256*32]; u16 Bs[2][64*32]; } s;
    float C[64][65];
  } u;
  const int tid = threadIdx.x, wv = tid>>6, ln = tid&63;
  const int lrow = ln&15, lk = ln>>4;
  int id = blockIdx.x;
  int low = id & 7, hi = id >> 3;
  int half = hi & 1;
  int tb = (hi>>1) & 7;
  int b  = ((hi >> 4) << 3) | low;
  const size_t base = (size_t)b*L_SEQ*512;
  f32x4 acc[4][4];
  #pragma unroll
  for (int i=0;i<4;i++)
    #pragma unroll
    for (int j=0;j<4;j++) acc[i][j] = f32x4{0.f,0.f,0.f,0.f};

  auto stageG = [&](int buf, int it){
    int jt = half*12 + (it>>3), dt = it&7;
    int t0 = tb*192 + jt*64, d0 = dt*32;
    #pragma unroll
    for (int p=0;p<4;p++){
      int chunk = (p*4+wv)*64 + ln;
      int row = chunk>>2, c16 = chunk&3;
      int sw = (row>>1)&3;
      int g = t0 + row; if (g >= L_SEQ) g -= L_SEQ;
      load_lds16(Q2 + base + (size_t)g*512 + d0 + ((c16^sw)*8), &u.s.As[buf][(size_t)chunk*8]);
    }
    { int chunk = wv*64 + ln;
      int row = chunk>>2, c16 = chunk&3;
      int sw = (row>>1)&3;
      load_lds16(K2 + base + (size_t)(jt*64+row)*512 + d0 + ((c16^sw)*8), &u.s.Bs[buf][(size_t)chunk*8]); }
  };

  stageG(0, 0);
  int cur = 0;
  const int swR = (lrow>>1)&3;
  for (int it = 0; it < 96; it++){
    __syncthreads();
    if (it+1 < 96) stageG(cur^1, it+1);
    half8 av[4], bv[4];
    #pragma unroll
    for (int mi=0;mi<4;mi++) av[mi] = *(const half8*)&u.s.As[cur][(wv*64 + mi*16 + lrow)*32 + ((lk^swR)*8)];
    #pragma unroll
    for (int ni=0;ni<4;ni++) bv[ni] = *(const half8*)&u.s.Bs[cur][(ni*16 + lrow)*32 + ((lk^swR)*8)];
    #pragma unroll
    for (int mi=0;mi<4;mi++)
      #pragma unroll
      for (int ni=0;ni<4;ni++)
        acc[mi][ni] = mfma_fp(av[mi], bv[ni], acc[mi][ni]);
    cur ^= 1;
  }
  __syncthreads();

  float dsum = 0.f;
  for (int r = 0; r < 4; r++){
    if (wv == r){
      #pragma unroll
      for (int mi=0;mi<4;mi++)
        #pragma unroll
        for (int ni=0;ni<4;ni++)
          #pragma unroll
          for (int rr=0;rr<4;rr++)
            u.C[mi*16 + lk*4 + rr][ni*16 + lrow] = acc[mi][ni][rr];
    }
    __syncthreads();
    if (tid < 192){
      int jlo = r*64 - tid;      if (jlo < 0) jlo = 0;
      int jhi = r*64 + 64 - tid; if (jhi > 64) jhi = 64;
      for (int j = jlo; j < jhi; j++) dsum += u.C[tid + j - r*64][j];
    }
    __syncthreads();
  }
  if (tid < 192) MCP[(size_t)half*GRAM_PLANE + (size_t)b*L_SEQ + tb*192 + tid] = dsum * (1.f/256.f);
}

// ---------- top-16 candidates + margin (sums the two jt-half planes) ----------
__global__ __launch_bounds__(256) void topk_k(const float* __restrict__ MCP, int* __restrict__ CANDI,
                                              int* __restrict__ NCAND){
  __shared__ float v[1536];
  __shared__ float rv[256]; __shared__ int ri[256];
  __shared__ float sred[256];
  __shared__ float s_margin;
  __shared__ float topv[16]; __shared__ int topi[16];
  int b = blockIdx.x, tid = threadIdx.x;
  const float* r0 = MCP + (size_t)b*L_SEQ;
  const float* r1 = MCP + GRAM_PLANE + (size_t)b*L_SEQ;
  float s = 0.f, ss = 0.f;
  for (int j=0;j<6;j++){
    int idx = tid+256*j;
    float x = r0[idx] + r1[idx];
    v[idx] = x; s += x; ss += x*x;
  }
  sred[tid]=s; __syncthreads();
  for (int o=128;o>0;o>>=1){ if (tid<o) sred[tid]+=sred[tid+o]; __syncthreads(); }
  float mean = sred[0]*(1.f/1536.f); __syncthreads();
  sred[tid]=ss; __syncthreads();
  for (int o=128;o>0;o>>=1){ if (tid<o) sred[tid]+=sred[tid+o]; __syncthreads(); }
  if (tid==0){
    float var = sred[0]*(1.f/1536.f) - mean*mean; if (var < 0.f) var = 0.f;
    s_margin = 0.02f*sqrtf(var) + 1e-8f;
  }
  __syncthreads();
  for (int it = 0; it < 16; it++){
    float bv_ = -3.4e38f; int bi_ = 1<<30;
    for (int j=0;j<6;j++){ int idx = tid+256*j; float x = v[idx];
      if (x > bv_ || (x == bv_ && idx < bi_)){ bv_ = x; bi_ = idx; } }
    rv[tid]=bv_; ri[tid]=bi_; __syncthreads();
    for (int o=128;o>0;o>>=1){
      if (tid<o){
        float xo = rv[tid+o]; int io = ri[tid+o];
        if (xo > rv[tid] || (xo == rv[tid] && io < ri[tid])){ rv[tid]=xo; ri[tid]=io; }
      }
      __syncthreads();
    }
    if (tid==0){ topv[it]=rv[0]; topi[it]=ri[0]; v[ri[0]] = -3.4e38f; }
    __syncthreads();
  }
  if (tid==0){
    float thr = topv[6] - s_margin;
    int nc = 7; while (nc < 16 && topv[nc] >= thr) nc++;
    NCAND[b] = nc;
    for (int i=0;i<16;i++) CANDI[b*16+i] = topi[i];
  }
}

// ---------- exact fp16-pair recompute: 4 candidates per block ----------
// id = (b&7) + 8*( cg + 4*(b>>3) ); candidates cg*4 .. cg*4+3
__global__ __launch_bounds__(256) void recompute4_k(const u16* __restrict__ Q2, const u16* __restrict__ K2,
                                                    const int* __restrict__ CANDI, const int* __restrict__ NCAND,
                                                    float* __restrict__ CANDV){
  int id = blockIdx.x;
  int low = id & 7, hi = id >> 3;
  int cg = hi & 3;
  int b = ((hi >> 2) << 3) | low;
  int nc = NCAND[b];
  int c0 = cg*4;
  if (c0 >= nc) return;
  int tau[4];
  #pragma unroll
  for (int i=0;i<4;i++){
    int ci = c0+i; if (ci > 15) ci = 15;
    tau[i] = CANDI[b*16+ci];
  }
  const half_t* qb = (const half_t*)Q2 + (size_t)b*L_SEQ*512;
  const half_t* kb = (const half_t*)K2 + (size_t)b*L_SEQ*512;
  int tid = threadIdx.x, wv = tid>>6, ln = tid&63;
  int d0 = ln*4;
  float acc[4] = {0.f,0.f,0.f,0.f};
  #pragma unroll 2
  for (int t = wv; t < L_SEQ; t += 4){
    half4 kh = *(const half4*)(kb + (size_t)t*512 + d0);
    half4 kl = *(const half4*)(kb + (size_t)t*512 + 256 + d0);
    float kv[4];
    #pragma unroll
    for (int j=0;j<4;j++) kv[j] = (float)kh[j] + (float)kl[j]*(1.f/512.f);
    #pragma unroll
    for (int i=0;i<4;i++){
      int g = t + tau[i]; if (g >= L_SEQ) g -= L_SEQ;
      const half_t* qr = qb + (size_t)g*512 + d0;
      half4 qh = *(const half4*)qr;
      half4 ql = *(const half4*)(qr+256);
      #pragma unroll
      for (int j=0;j<4;j++)
        acc[i] += ((float)qh[j] + (float)ql[j]*(1.f/512.f))*kv[j];
    }
  }
  #pragma unroll
  for (int i=0;i<4;i++)
    #pragma unroll
    for (int o=32;o>0;o>>=1) acc[i] += __shfl_xor(acc[i],o);
  __shared__ float red[4][4];
  if (ln==0){
    #pragma unroll
    for (int i=0;i<4;i++) red[wv][i] = acc[i];
  }
  __syncthreads();
  if (tid < 4){
    int ci = c0 + tid;
    if (ci < nc)
      CANDV[b*16+ci] = (red[0][tid]+red[1][tid]+red[2][tid]+red[3][tid])*(1.f/256.f);
  }
}

// ---------- final top-7 by exact value + softmax ----------
__global__ void select7_k(const int* __restrict__ CANDI, const float* __restrict__ CANDV,
                          const int* __restrict__ NCAND, int* __restrict__ DLY, float* __restrict__ WGT){
  int b = blockIdx.x;
  if (threadIdx.x != 0) return;
  int nc = NCAND[b];
  float vals[16]; int idx[16];
  #pragma unroll
  for (int i=0;i<16;i++){ vals[i] = (i<nc)? CANDV[b*16+i] : -3.4e38f; idx[i] = CANDI[b*16+i]; }
  for (int i=0;i<7;i++){
    int best=i;
    for (int j=i+1;j<16;j++)
      if (vals[j]>vals[best] || (vals[j]==vals[best] && idx[j]<idx[best])) best=j;
    float tv=vals[i]; vals[i]=vals[best]; vals[best]=tv;
    int ti=idx[i]; idx[i]=idx[best]; idx[best]=ti;
  }
  float m=vals[0], e[7], sum=0.f;
  #pragma unroll
  for (int i=0;i<7;i++){ e[i]=expf(vals[i]-m); sum+=e[i]; }
  #pragma unroll
  for (int i=0;i<7;i++){ WGT[b*8+i]=e[i]/sum; DLY[b*8+i]=idx[i]; }
}

// ---------- weighted circular-delay aggregation (bf16) ----------
__global__ __launch_bounds__(256) void agg_k(const u16* __restrict__ V, const int* __restrict__ DLY,
                                             const float* __restrict__ WGT, u16* __restrict__ AGG){
  int gid = blockIdx.x*256 + threadIdx.x;       // unit = 8 bf16
  int b = gid / 49152;
  int rem = gid % 49152;
  int t = rem >> 5, du = rem & 31;
  float w[7]; int dl[7];
  #pragma unroll
  for (int i=0;i<7;i++){ w[i]=WGT[b*8+i]; dl[i]=DLY[b*8+i]; }
  float a[8] = {0,0,0,0,0,0,0,0};
  #pragma unroll
  for (int i=0;i<7;i++){
    int g = t + dl[i]; if (g >= L_SEQ) g -= L_SEQ;
    short8 hv = *(const short8*)(V + ((size_t)b*L_SEQ + g)*256 + du*8);
    #pragma unroll
    for (int j=0;j<8;j++) a[j] += w[i]*bf2f((u16)hv[j]);
  }
  short8 o;
  #pragma unroll
  for (int j=0;j<8;j++) o[j] = (short)f2bf(a[j]);
  *(short8*)(AGG + ((size_t)b*L_SEQ + t)*256 + du*8) = o;
}

// ---------- series decomp: x = s - movavg(s, 25, replicate-pad); store bf16 pair ----------
__global__ __launch_bounds__(256) void decomp_k(const float* __restrict__ S, u16* __restrict__ X2B){
  int b = blockIdx.y, lc = blockIdx.x, d = threadIdx.x;
  const float* s = S + (size_t)b*L_SEQ*256;
  int l0 = lc*128;
  float w = 0.f;
  for (int j=-12;j<=12;j++){
    int g = l0+j; if (g < 0) g = 0; if (g > L_SEQ-1) g = L_SEQ-1;
    w += s[(size_t)g*256+d];
  }
  for (int l = l0; l < l0+128; l++){
    float c = s[(size_t)l*256+d];
    store_pair(c - w*(1.f/25.f), (size_t)b*L_SEQ + l, d, X2B);
    int ga = l+13; if (ga > L_SEQ-1) ga = L_SEQ-1;
    int gb = l-12; if (gb < 0) gb = 0;
    w += s[(size_t)ga*256+d] - s[(size_t)gb*256+d];
  }
}

// ---------- fused final LN + column (seq) partial reduce ----------
__global__ __launch_bounds__(256) void lncr_k(const u16* __restrict__ X2B, const float* __restrict__ LW,
                                              const float* __restrict__ LB, float* __restrict__ RS,
                                              float* __restrict__ RM){
  int b = blockIdx.y, lc = blockIdx.x;
  int tid = threadIdx.x, wv = tid>>6, l_ = tid&63;
  f32x4 lw = *(const f32x4*)(LW + l_*4);
  f32x4 lb = *(const f32x4*)(LB + l_*4);
  float cs[4] = {0,0,0,0};
  float cm[4] = {-3.4e38f,-3.4e38f,-3.4e38f,-3.4e38f};
  size_t tok0 = (size_t)b*L_SEQ + lc*128 + wv*32;
  for (int it = 0; it < 32; it++){
    const u16* xr = X2B + (tok0+it)*512 + l_*4;
    u16x4 hi = *(const u16x4*)xr;
    u16x4 lo = *(const u16x4*)(xr+256);
    float v[4]; float s=0.f, ss=0.f;
    #pragma unroll
    for (int j=0;j<4;j++){ v[j] = bf2f(hi[j]) + bf2f(lo[j]); s += v[j]; ss += v[j]*v[j]; }
    #pragma unroll
    for (int o=32;o>0;o>>=1){ s += __shfl_xor(s,o); ss += __shfl_xor(ss,o); }
    float mean = s*(1.f/256.f);
    float var = ss*(1.f/256.f) - mean*mean;
    float rstd = rsqrtf(var + 1e-5f);
    #pragma unroll
    for (int j=0;j<4;j++){
      float xh = (v[j]-mean)*rstd*lw[j] + lb[j];
      cs[j] += xh; cm[j] = fmaxf(cm[j], xh);
    }
  }
  __shared__ float S[4][256];
  __shared__ float M[4][256];
  #pragma unroll
  for (int j=0;j<4;j++){ S[wv][l_*4+j] = cs[j]; M[wv][l_*4+j] = cm[j]; }
  __syncthreads();
  float s4 = S[0][tid]+S[1][tid]+S[2][tid]+S[3][tid];
  float m4 = fmaxf(fmaxf(M[0][tid],M[1][tid]), fmaxf(M[2][tid],M[3][tid]));
  RS[((size_t)b*12+lc)*256+tid] = s4;
  RM[((size_t)b*12+lc)*256+tid] = m4;
}

// ---------- combine partials, gelu features, 176-proj ----------
__global__ __launch_bounds__(256) void final_k(const float* __restrict__ RS, const float* __restrict__ RM,
                                               const float* __restrict__ PW, const float* __restrict__ PB,
                                               float* __restrict__ OUT){
  __shared__ float feat[256];
  int b = blockIdx.x, tid = threadIdx.x;
  float s = 0.f, m = -3.4e38f;
  for (int c=0;c<12;c++){
    s += RS[((size_t)b*12+c)*256+tid];
    m = fmaxf(m, RM[((size_t)b*12+c)*256+tid]);
  }
  float mu = s*(1.f/1536.f);
  feat[tid] = gelu_f(m - mu);
  __syncthreads();
  if (tid < 176){
    float acc = PB[tid];
    for (int d=0; d<256; d++) acc += feat[d]*PW[(size_t)tid*512 + 256 + d];
    OUT[(size_t)b*176 + tid] = acc;
  }
}

// ================= host launch =================
extern "C" void kernel_launch(void* const* d_in, const int* in_sizes, int n_in,
                              void* d_out, int out_size, void* d_ws, size_t ws_size,
                              hipStream_t stream){
  const float* x_enc=(const float*)d_in[0];
  const float* emb_w=(const float*)d_in[1];
  const float* Wq=(const float*)d_in[2];  const float* bq=(const float*)d_in[3];
  const float* Wk=(const float*)d_in[4];  const float* bk=(const float*)d_in[5];
  const float* Wv=(const float*)d_in[6];  const float* bv=(const float*)d_in[7];
  const float* Wo=(const float*)d_in[8];  const float* bo=(const float*)d_in[9];
  const float* Wc1=(const float*)d_in[10]; const float* bc1=(const float*)d_in[11];
  const float* Wc2=(const float*)d_in[12]; const float* bc2=(const float*)d_in[13];
  const float* ln_w=(const float*)d_in[14]; const float* ln_b=(const float*)d_in[15];
  const float* pw=(const float*)d_in[16];  const float* pb=(const float*)d_in[17];
  (void)in_sizes; (void)n_in; (void)out_size;

  // adaptive batch-grouping so workspace fits ws_size
  int G = 1;
  while (G < 8){
    size_t need = (size_t)40*1024*1024 + (7ull*(size_t)(98304/G)*1024ull)/2;
    if (need <= ws_size) break;
    G *= 2;
  }
  const int NBG = 64 / G;            // batches per group
  const int NT  = NBG * L_SEQ;       // tokens per group

  char* ws = (char*)d_ws;
  size_t off = 0;
  auto alloc = [&](size_t bytes)->void*{
    void* p = ws + off; off += (bytes + 255) & ~(size_t)255; return p;
  };
  u16* W4QKV = (u16*)alloc((size_t)2*768*768*2);   // per layer: [Wq3;Wk3;WvPad], ldb 768
  u16* WOb  = (u16*)alloc((size_t)2*256*256*2);
  u16* WC1b = (u16*)alloc((size_t)2*1024*256*2);
  u16* WC2b = (u16*)alloc((size_t)2*256*1024*2);
  float* MCP = (float*)alloc((size_t)2*GRAM_PLANE*4);
  int*  CANDI=(int*)  alloc(64*16*4);
  float*CANDV=(float*)alloc(64*16*4);
  int*  NCAND=(int*)  alloc(64*4);
  int*  DLY = (int*)  alloc(64*8*4);
  float*WGT = (float*)alloc(64*8*4);
  float*RS  = (float*)alloc((size_t)64*12*256*4);
  float*RM  = (float*)alloc((size_t)64*12*256*4);
  u16* X2B = (u16*)alloc((size_t)NT*512*2);   // master activation: bf16 hi/lo pairs
  u16* Q2  = (u16*)alloc((size_t)NT*512*2);   // fp16 hi/lo pairs; aliased by AGG/HH
  u16* K2  = (u16*)alloc((size_t)NT*512*2);   // fp16 hi/lo pairs; aliased by SUM (f32)
  u16* V2  = (u16*)alloc((size_t)NT*256*2);   // bf16

  float* SUM = (float*)K2;
  u16*   AGG = Q2;
  u16*   HH  = Q2;

  // weight prep (once per call)
  for (int l = 0; l < 2; l++){
    w4b768_k<<<256,256,0,stream>>>(Wq + (size_t)l*65536, W4QKV + ((size_t)l*768+  0)*768, 65536);
    w4b768_k<<<256,256,0,stream>>>(Wk + (size_t)l*65536, W4QKV + ((size_t)l*768+256)*768, 65536);
    wvpad_k <<<256,256,0,stream>>>(Wv + (size_t)l*65536, W4QKV + ((size_t)l*768+512)*768, 65536);
  }
  castb_k<<<512,256,0,stream>>>(Wo, WOb, 2*256*256);
  castb_k<<<2048,256,0,stream>>>(Wc1, WC1b, 2*1024*256);
  castb_k<<<2048,256,0,stream>>>(Wc2, WC2b, 2*256*1024);

  for (int g = 0; g < G; g++){
    const float* xe = x_enc + (size_t)g*NBG*L_SEQ*7;
    float* outg = (float*)d_out + (size_t)g*NBG*176;

    embed_k<<<NT/64,256,0,stream>>>(xe, emb_w, X2B);

    for (int l = 0; l < 2; l++){
      // unified Q/K/V projections (QK: split-bf16 K=768, V: K=256)
      gemmqkv_k<<<dim3(NT/128,6),256,0,stream>>>(X2B, W4QKV+(size_t)l*768*768,
                                                 bq+l*256, bk+l*256, bv+l*256, Q2, K2, V2);
      // mean correlation via banded circular gram (fp16 stage-1), jt-split x2
      gram_k<<<NBG*16,256,0,stream>>>(Q2, K2, MCP);
      topk_k<<<NBG,256,0,stream>>>(MCP, CANDI, NCAND);
      recompute4_k<<<NBG*4,256,0,stream>>>(Q2, K2, CANDI, NCAND, CANDV);
      select7_k<<<NBG,64,0,stream>>>(CANDI, CANDV, NCAND, DLY, WGT);
      // weighted circular-delay aggregation (AGG aliases Q2)
      agg_k<<<NT/8,256,0,stream>>>(V2, DLY, WGT, AGG);
      // Wo + residual -> SUM (f32, aliases K2)
      gemm_k<2,false><<<dim3(NT/128,2),256,0,stream>>>(AGG,256, WOb+(size_t)l*65536,256, bo+l*256, SUM, 256, X2B, 256);
      decomp_k<<<dim3(12,NBG),256,0,stream>>>(SUM, X2B);
      // FFN in 2 M-chunks (HH aliases full Q2 region)
      for (int c = 0; c < 2; c++){
        const u16* Ac = X2B + (size_t)c*(NT/2)*512;
        gemm_k<1,false><<<dim3(NT/256,8),256,0,stream>>>(Ac,512, WC1b+(size_t)l*262144,256, bc1+l*1024, HH, 1024, nullptr, 256);
        gemm_k<2,false><<<dim3(NT/256,2),256,0,stream>>>(HH,1024, WC2b+(size_t)l*262144,1024, bc2+l*256,
                                                         SUM+(size_t)c*(NT/2)*256, 256, X2B+(size_t)c*(NT/2)*512, 1024);
      }
      decomp_k<<<dim3(12,NBG),256,0,stream>>>(SUM, X2B);
    }

    lncr_k<<<dim3(12,NBG),256,0,stream>>>(X2B, ln_w, ln_b, RS, RM);
    final_k<<<NBG,256,0,stream>>>(RS, RM, pw, pb, outg);
  }
}

// Round 10
// 2211.432 us; speedup vs baseline: 1.1718x; 1.1718x over previous
//
#include <hip/hip_runtime.h>
#include <math.h>

typedef _Float16 half_t;
typedef _Float16 half4 __attribute__((ext_vector_type(4)));
typedef _Float16 half8 __attribute__((ext_vector_type(8)));
typedef short short8 __attribute__((ext_vector_type(8)));
typedef float f32x4 __attribute__((ext_vector_type(4)));
typedef unsigned short u16;
typedef unsigned short u16x4 __attribute__((ext_vector_type(4)));

#define L_SEQ 1536
#define GRAM_PLANE (64*1536)

// ---------- helpers ----------
__device__ __forceinline__ u16 f2bf(float f){
  unsigned u = __float_as_uint(f);
  return (u16)((u + 0x7FFFu + ((u>>16)&1u)) >> 16);
}
__device__ __forceinline__ float bf2f(u16 h){ return __uint_as_float(((unsigned)h)<<16); }
__device__ __forceinline__ float gelu_f(float x){ return 0.5f*x*(1.f+erff(x*0.70710678118f)); }

__device__ __forceinline__ void load_lds16(const void* g, void* l){
  __builtin_amdgcn_global_load_lds((const __attribute__((address_space(1))) void*)g,
                                   (__attribute__((address_space(3))) void*)l, 16, 0, 0);
}
__device__ __forceinline__ f32x4 mfma_bf(short8 a, short8 b, f32x4 c){
  return __builtin_amdgcn_mfma_f32_16x16x32_bf16(a,b,c,0,0,0);
}
__device__ __forceinline__ f32x4 mfma_fp(half8 a, half8 b, f32x4 c){
  return __builtin_amdgcn_mfma_f32_16x16x32_f16(a,b,c,0,0,0);
}

// store activation as bf16 hi/lo pair, row stride 512
__device__ __forceinline__ void store_pair(float v, size_t row, int d, u16* X2B){
  size_t r2 = row*512 + d;
  u16 hi = f2bf(v);
  X2B[r2] = hi;
  X2B[r2+256] = f2bf(v - bf2f(hi));
}

// ---------- weight prep ----------
__global__ __launch_bounds__(256) void w4b_k(const float* __restrict__ W, u16* __restrict__ W4, int n){
  int i = blockIdx.x*256 + threadIdx.x;
  if (i >= n) return;
  int ro = i >> 8, c = i & 255;
  float v = W[i];
  u16 hi = f2bf(v);
  u16 lo = f2bf(v - bf2f(hi));
  u16* r = W4 + (size_t)ro*1024;
  r[c] = hi; r[c+256] = hi; r[c+512] = lo; r[c+768] = lo;
}
__global__ __launch_bounds__(256) void castb_k(const float* __restrict__ W, u16* __restrict__ Wb, int n){
  for (int i = blockIdx.x*256 + threadIdx.x; i < n; i += gridDim.x*256)
    Wb[i] = f2bf(W[i]);
}

// ---------- embedding: circular conv1d k=3, 7->256; 64 tokens per block ----------
__global__ __launch_bounds__(256) void embed_k(const float* __restrict__ XE, const float* __restrict__ EW,
                                               u16* __restrict__ X2B){
  __shared__ float xs[66*7];
  int b = blockIdx.x / 24, lc = blockIdx.x % 24;
  int l0 = lc*64;
  int tid = threadIdx.x;
  for (int i = tid; i < 66*7; i += 256){
    int r = i/7, c = i%7;
    int g = l0 - 1 + r; if (g < 0) g += L_SEQ; if (g >= L_SEQ) g -= L_SEQ;
    xs[i] = XE[((size_t)b*L_SEQ + g)*7 + c];
  }
  __syncthreads();
  int d = tid;
  float wp[21];
  #pragma unroll
  for (int i=0;i<21;i++) wp[i] = EW[d*21+i];
  for (int j = 0; j < 64; j++){
    float acc = 0.f;
    #pragma unroll
    for (int c = 0; c < 7; c++)
      #pragma unroll
      for (int k = 0; k < 3; k++) acc += xs[(j+k)*7+c] * wp[c*3+k];
    store_pair(acc, (size_t)b*L_SEQ + l0 + j, d, X2B);
  }
}

// ---------- 128x128 MFMA bf16 GEMM: 2-phase prefetch, dbuf LDS, XOR-swizzled reads ----------
// bm = blockIdx.x (fastest), bn = blockIdx.y
// EPI: 0 = bf16 store, 1 = bf16 gelu store, 2 = f32 store + residual(pair)
template<int EPI, bool KMOD>
__global__ __launch_bounds__(256) void gemm_k(const u16* __restrict__ A, int lda,
                                              const u16* __restrict__ B, int ldb,
                                              const float* __restrict__ bias,
                                              void* __restrict__ C, int ldc,
                                              const u16* __restrict__ res,
                                              int K){
  __shared__ __align__(16) u16 As[2][128*32];
  __shared__ __align__(16) u16 Bs[2][128*32];
  const int tid = threadIdx.x;
  const int wv = tid>>6, ln = tid&63;
  const int lrow = ln&15, lk = ln>>4;
  const int bm = blockIdx.x, bn = blockIdx.y;
  const int wr = wv>>1, wc = wv&1;
  f32x4 acc[4][4];
  #pragma unroll
  for (int i=0;i<4;i++)
    #pragma unroll
    for (int j=0;j<4;j++) acc[i][j] = f32x4{0.f,0.f,0.f,0.f};

  const int nt = K >> 5;
  auto stage = [&](int buf, int t){
    int k0 = t*32;
    int ka = KMOD ? (k0 & 511) : k0;
    #pragma unroll
    for (int p=0;p<2;p++){
      int chunk = (wv*2+p)*64 + ln;
      int row = chunk>>2, c16 = chunk&3;
      int sw = (row>>1)&3;
      load_lds16(A + (size_t)(bm*128 + row)*lda + (ka + ((c16^sw)*8)), &As[buf][(size_t)chunk*8]);
      load_lds16(B + (size_t)(bn*128 + row)*ldb + (k0 + ((c16^sw)*8)), &Bs[buf][(size_t)chunk*8]);
    }
  };

  stage(0, 0);
  int cur = 0;
  const int swR = (lrow>>1)&3;
  for (int t = 0; t < nt; t++){
    __syncthreads();
    if (t+1 < nt) stage(cur^1, t+1);
    short8 av[4], bv[4];
    #pragma unroll
    for (int mi=0;mi<4;mi++) av[mi] = *(const short8*)&As[cur][(wr*64 + mi*16 + lrow)*32 + ((lk^swR)*8)];
    #pragma unroll
    for (int ni=0;ni<4;ni++) bv[ni] = *(const short8*)&Bs[cur][(wc*64 + ni*16 + lrow)*32 + ((lk^swR)*8)];
    #pragma unroll
    for (int mi=0;mi<4;mi++)
      #pragma unroll
      for (int ni=0;ni<4;ni++)
        acc[mi][ni] = mfma_bf(av[mi], bv[ni], acc[mi][ni]);
    cur ^= 1;
  }

  #pragma unroll
  for (int mi=0;mi<4;mi++){
    #pragma unroll
    for (int ni=0;ni<4;ni++){
      int col = bn*128 + wc*64 + ni*16 + lrow;
      float bs = bias[col];
      #pragma unroll
      for (int r=0;r<4;r++){
        int row = bm*128 + wr*64 + mi*16 + lk*4 + r;
        float v = acc[mi][ni][r] + bs;
        if (EPI==0){ ((u16*)C)[(size_t)row*ldc + col] = f2bf(v); }
        else if (EPI==1){ ((u16*)C)[(size_t)row*ldc + col] = f2bf(gelu_f(v)); }
        else {
          float rv = bf2f(res[(size_t)row*512 + col]) + bf2f(res[(size_t)row*512 + 256 + col]);
          ((float*)C)[(size_t)row*ldc + col] = v + rv;
        }
      }
    }
  }
}

// ---------- merged QK projection GEMM: N=512, split-bf16 K=1024 fused ----------
// bm = blockIdx.x; bn = blockIdx.y: 0-1 -> Q (fp16 pair out), 2-3 -> K (fp16 pair out)
__global__ __launch_bounds__(256) void gemmqk_k(const u16* __restrict__ A,
                                                const u16* __restrict__ B,   // [512,1024] layer slice
                                                const float* __restrict__ bq,
                                                const float* __restrict__ bk,
                                                u16* __restrict__ Q2, u16* __restrict__ K2){
  __shared__ __align__(16) u16 As[2][128*32];
  __shared__ __align__(16) u16 Bs[2][128*32];
  const int tid = threadIdx.x;
  const int wv = tid>>6, ln = tid&63;
  const int lrow = ln&15, lk = ln>>4;
  const int bm = blockIdx.x, bn = blockIdx.y;
  const int wr = wv>>1, wc = wv&1;
  f32x4 acc[4][4];
  #pragma unroll
  for (int i=0;i<4;i++)
    #pragma unroll
    for (int j=0;j<4;j++) acc[i][j] = f32x4{0.f,0.f,0.f,0.f};

  auto stage = [&](int buf, int t){
    int k0 = t*32;
    int ka = k0 & 511;
    #pragma unroll
    for (int p=0;p<2;p++){
      int chunk = (wv*2+p)*64 + ln;
      int row = chunk>>2, c16 = chunk&3;
      int sw = (row>>1)&3;
      load_lds16(A + (size_t)(bm*128 + row)*512 + (ka + ((c16^sw)*8)), &As[buf][(size_t)chunk*8]);
      load_lds16(B + (size_t)(bn*128 + row)*1024 + (k0 + ((c16^sw)*8)), &Bs[buf][(size_t)chunk*8]);
    }
  };

  stage(0, 0);
  int cur = 0;
  const int swR = (lrow>>1)&3;
  for (int t = 0; t < 32; t++){
    __syncthreads();
    if (t+1 < 32) stage(cur^1, t+1);
    short8 av[4], bv_[4];
    #pragma unroll
    for (int mi=0;mi<4;mi++) av[mi] = *(const short8*)&As[cur][(wr*64 + mi*16 + lrow)*32 + ((lk^swR)*8)];
    #pragma unroll
    for (int ni=0;ni<4;ni++) bv_[ni] = *(const short8*)&Bs[cur][(wc*64 + ni*16 + lrow)*32 + ((lk^swR)*8)];
    #pragma unroll
    for (int mi=0;mi<4;mi++)
      #pragma unroll
      for (int ni=0;ni<4;ni++)
        acc[mi][ni] = mfma_bf(av[mi], bv_[ni], acc[mi][ni]);
    cur ^= 1;
  }

  const int proj = bn>>1, half = bn&1;
  const float* bias = (proj==0) ? bq : bk;
  half_t* Cp = (half_t*)((proj==0) ? Q2 : K2);
  #pragma unroll
  for (int mi=0;mi<4;mi++){
    #pragma unroll
    for (int ni=0;ni<4;ni++){
      int col = half*128 + wc*64 + ni*16 + lrow;
      float bs = bias[col];
      #pragma unroll
      for (int r=0;r<4;r++){
        int row = bm*128 + wr*64 + mi*16 + lk*4 + r;
        float v = acc[mi][ni][r] + bs;
        half_t hi = (half_t)v;
        Cp[(size_t)row*512 + col] = hi;
        Cp[(size_t)row*512 + 256 + col] = (half_t)((v - (float)hi)*512.f);
      }
    }
  }
}

// ---------- banded circular gram + diagonal reduce; jt-split x2, 2-phase prefetch + swizzle ----------
// id = low3(b) | 8*( half + 2*tb + 16*(b>>3) )
__global__ __launch_bounds__(256) void gram_k(const u16* __restrict__ Q2, const u16* __restrict__ K2,
                                              float* __restrict__ MCP){
  __shared__ __align__(16) union UN {
    struct { u16 As[2][256*32]; u16 Bs[2][64*32]; } s;
    float C[64][65];
  } u;
  const int tid = threadIdx.x, wv = tid>>6, ln = tid&63;
  const int lrow = ln&15, lk = ln>>4;
  int id = blockIdx.x;
  int low = id & 7, hi = id >> 3;
  int half = hi & 1;
  int tb = (hi>>1) & 7;
  int b  = ((hi >> 4) << 3) | low;
  const size_t base = (size_t)b*L_SEQ*512;
  f32x4 acc[4][4];
  #pragma unroll
  for (int i=0;i<4;i++)
    #pragma unroll
    for (int j=0;j<4;j++) acc[i][j] = f32x4{0.f,0.f,0.f,0.f};

  auto stageG = [&](int buf, int it){
    int jt = half*12 + (it>>3), dt = it&7;
    int t0 = tb*192 + jt*64, d0 = dt*32;
    #pragma unroll
    for (int p=0;p<4;p++){
      int chunk = (p*4+wv)*64 + ln;
      int row = chunk>>2, c16 = chunk&3;
      int sw = (row>>1)&3;
      int g = t0 + row; if (g >= L_SEQ) g -= L_SEQ;
      load_lds16(Q2 + base + (size_t)g*512 + d0 + ((c16^sw)*8), &u.s.As[buf][(size_t)chunk*8]);
    }
    { int chunk = wv*64 + ln;
      int row = chunk>>2, c16 = chunk&3;
      int sw = (row>>1)&3;
      load_lds16(K2 + base + (size_t)(jt*64+row)*512 + d0 + ((c16^sw)*8), &u.s.Bs[buf][(size_t)chunk*8]); }
  };

  stageG(0, 0);
  int cur = 0;
  const int swR = (lrow>>1)&3;
  for (int it = 0; it < 96; it++){
    __syncthreads();
    if (it+1 < 96) stageG(cur^1, it+1);
    half8 av[4], bv[4];
    #pragma unroll
    for (int mi=0;mi<4;mi++) av[mi] = *(const half8*)&u.s.As[cur][(wv*64 + mi*16 + lrow)*32 + ((lk^swR)*8)];
    #pragma unroll
    for (int ni=0;ni<4;ni++) bv[ni] = *(const half8*)&u.s.Bs[cur][(ni*16 + lrow)*32 + ((lk^swR)*8)];
    #pragma unroll
    for (int mi=0;mi<4;mi++)
      #pragma unroll
      for (int ni=0;ni<4;ni++)
        acc[mi][ni] = mfma_fp(av[mi], bv[ni], acc[mi][ni]);
    cur ^= 1;
  }
  __syncthreads();

  float dsum = 0.f;
  for (int r = 0; r < 4; r++){
    if (wv == r){
      #pragma unroll
      for (int mi=0;mi<4;mi++)
        #pragma unroll
        for (int ni=0;ni<4;ni++)
          #pragma unroll
          for (int rr=0;rr<4;rr++)
            u.C[mi*16 + lk*4 + rr][ni*16 + lrow] = acc[mi][ni][rr];
    }
    __syncthreads();
    if (tid < 192){
      int jlo = r*64 - tid;      if (jlo < 0) jlo = 0;
      int jhi = r*64 + 64 - tid; if (jhi > 64) jhi = 64;
      for (int j = jlo; j < jhi; j++) dsum += u.C[tid + j - r*64][j];
    }
    __syncthreads();
  }
  if (tid < 192) MCP[(size_t)half*GRAM_PLANE + (size_t)b*L_SEQ + tb*192 + tid] = dsum * (1.f/256.f);
}

// ---------- top-16 + provisional selection from gram values; flag ambiguity ----------
// gram noise ~7e-4*sigma; ambiguity thr = 0.004*sigma (~6x noise); exact-margin = 0.02*sigma
__global__ __launch_bounds__(256) void topk_k(const float* __restrict__ MCP, int* __restrict__ CANDI,
                                              int* __restrict__ NEEDEX, int* __restrict__ DLY,
                                              float* __restrict__ WGT){
  __shared__ float v[1536];
  __shared__ float rv[256]; __shared__ int ri[256];
  __shared__ float sred[256];
  __shared__ float s_margin;
  __shared__ float topv[16]; __shared__ int topi[16];
  int b = blockIdx.x, tid = threadIdx.x;
  const float* r0 = MCP + (size_t)b*L_SEQ;
  const float* r1 = MCP + GRAM_PLANE + (size_t)b*L_SEQ;
  float s = 0.f, ss = 0.f;
  for (int j=0;j<6;j++){
    int idx = tid+256*j;
    float x = r0[idx] + r1[idx];
    v[idx] = x; s += x; ss += x*x;
  }
  sred[tid]=s; __syncthreads();
  for (int o=128;o>0;o>>=1){ if (tid<o) sred[tid]+=sred[tid+o]; __syncthreads(); }
  float mean = sred[0]*(1.f/1536.f); __syncthreads();
  sred[tid]=ss; __syncthreads();
  for (int o=128;o>0;o>>=1){ if (tid<o) sred[tid]+=sred[tid+o]; __syncthreads(); }
  if (tid==0){
    float var = sred[0]*(1.f/1536.f) - mean*mean; if (var < 0.f) var = 0.f;
    s_margin = 0.02f*sqrtf(var) + 1e-8f;
  }
  __syncthreads();
  for (int it = 0; it < 16; it++){
    float bv_ = -3.4e38f; int bi_ = 1<<30;
    for (int j=0;j<6;j++){ int idx = tid+256*j; float x = v[idx];
      if (x > bv_ || (x == bv_ && idx < bi_)){ bv_ = x; bi_ = idx; } }
    rv[tid]=bv_; ri[tid]=bi_; __syncthreads();
    for (int o=128;o>0;o>>=1){
      if (tid<o){
        float xo = rv[tid+o]; int io = ri[tid+o];
        if (xo > rv[tid] || (xo == rv[tid] && io < ri[tid])){ rv[tid]=xo; ri[tid]=io; }
      }
      __syncthreads();
    }
    if (tid==0){ topv[it]=rv[0]; topi[it]=ri[0]; v[ri[0]] = -3.4e38f; }
    __syncthreads();
  }
  if (tid==0){
    float thr_amb = 0.2f*s_margin;          // 0.004*sigma
    int nc = 0;
    if (topv[7] >= topv[6] - thr_amb){      // rank-7/8 gap too small: needs exact resolve
      nc = 7;
      float thr = topv[6] - s_margin;
      while (nc < 16 && topv[nc] >= thr) nc++;
    }
    NEEDEX[b] = nc;
    for (int i=0;i<16;i++) CANDI[b*16+i] = topi[i];
    // provisional (final when nc==0) selection + softmax from gram values
    float m = topv[0], e[7], sum = 0.f;
    #pragma unroll
    for (int i=0;i<7;i++){ e[i] = expf(topv[i]-m); sum += e[i]; }
    #pragma unroll
    for (int i=0;i<7;i++){ WGT[b*8+i] = e[i]/sum; DLY[b*8+i] = topi[i]; }
  }
}

// ---------- exact fp16-pair recompute: one block per (batch, candidate); exits unless flagged ----------
__global__ __launch_bounds__(256) void recompute3_k(const u16* __restrict__ Q2, const u16* __restrict__ K2,
                                                    const int* __restrict__ CANDI, const int* __restrict__ NEEDEX,
                                                    float* __restrict__ CANDV){
  int id = blockIdx.x;
  int low = id & 7, hi = id >> 3;
  int ci = hi & 15;
  int b = (hi >> 4)*8 + low;
  if (ci >= NEEDEX[b]) return;          // NEEDEX==0 -> whole batch skipped
  int tau = CANDI[b*16+ci];
  const half_t* qb = (const half_t*)Q2 + (size_t)b*L_SEQ*512;
  const half_t* kb = (const half_t*)K2 + (size_t)b*L_SEQ*512;
  int tid = threadIdx.x, wv = tid>>6, ln = tid&63;
  int d0 = ln*4;
  float acc = 0.f;
  #pragma unroll 4
  for (int t = wv; t < L_SEQ; t += 4){
    int g = t + tau; if (g >= L_SEQ) g -= L_SEQ;
    half4 qh = *(const half4*)(qb + (size_t)g*512 + d0);
    half4 ql = *(const half4*)(qb + (size_t)g*512 + 256 + d0);
    half4 kh = *(const half4*)(kb + (size_t)t*512 + d0);
    half4 kl = *(const half4*)(kb + (size_t)t*512 + 256 + d0);
    #pragma unroll
    for (int j=0;j<4;j++){
      float qv = (float)qh[j] + (float)ql[j]*(1.f/512.f);
      float kv = (float)kh[j] + (float)kl[j]*(1.f/512.f);
      acc += qv*kv;
    }
  }
  #pragma unroll
  for (int o=32;o>0;o>>=1) acc += __shfl_xor(acc,o);
  __shared__ float w4[4];
  if (ln==0) w4[wv]=acc;
  __syncthreads();
  if (tid==0) CANDV[b*16+ci] = (w4[0]+w4[1]+w4[2]+w4[3])*(1.f/256.f);
}

// ---------- finalize flagged batches: exact top-7 + softmax ----------
__global__ void select7_k(const int* __restrict__ CANDI, const float* __restrict__ CANDV,
                          const int* __restrict__ NEEDEX, int* __restrict__ DLY, float* __restrict__ WGT){
  int b = blockIdx.x;
  if (threadIdx.x != 0) return;
  int nc = NEEDEX[b];
  if (nc == 0) return;                  // gram-based selection stands
  float vals[16]; int idx[16];
  #pragma unroll
  for (int i=0;i<16;i++){ vals[i] = (i<nc)? CANDV[b*16+i] : -3.4e38f; idx[i] = CANDI[b*16+i]; }
  for (int i=0;i<7;i++){
    int best=i;
    for (int j=i+1;j<16;j++)
      if (vals[j]>vals[best] || (vals[j]==vals[best] && idx[j]<idx[best])) best=j;
    float tv=vals[i]; vals[i]=vals[best]; vals[best]=tv;
    int ti=idx[i]; idx[i]=idx[best]; idx[best]=ti;
  }
  float m=vals[0], e[7], sum=0.f;
  #pragma unroll
  for (int i=0;i<7;i++){ e[i]=expf(vals[i]-m); sum+=e[i]; }
  #pragma unroll
  for (int i=0;i<7;i++){ WGT[b*8+i]=e[i]/sum; DLY[b*8+i]=idx[i]; }
}

// ---------- weighted circular-delay aggregation (bf16) ----------
__global__ __launch_bounds__(256) void agg_k(const u16* __restrict__ V, const int* __restrict__ DLY,
                                             const float* __restrict__ WGT, u16* __restrict__ AGG){
  int gid = blockIdx.x*256 + threadIdx.x;       // unit = 8 bf16
  int b = gid / 49152;
  int rem = gid % 49152;
  int t = rem >> 5, du = rem & 31;
  float w[7]; int dl[7];
  #pragma unroll
  for (int i=0;i<7;i++){ w[i]=WGT[b*8+i]; dl[i]=DLY[b*8+i]; }
  float a[8] = {0,0,0,0,0,0,0,0};
  #pragma unroll
  for (int i=0;i<7;i++){
    int g = t + dl[i]; if (g >= L_SEQ) g -= L_SEQ;
    short8 hv = *(const short8*)(V + ((size_t)b*L_SEQ + g)*256 + du*8);
    #pragma unroll
    for (int j=0;j<8;j++) a[j] += w[i]*bf2f((u16)hv[j]);
  }
  short8 o;
  #pragma unroll
  for (int j=0;j<8;j++) o[j] = (short)f2bf(a[j]);
  *(short8*)(AGG + ((size_t)b*L_SEQ + t)*256 + du*8) = o;
}

// ---------- series decomp: x = s - movavg(s, 25, replicate-pad); store bf16 pair ----------
__global__ __launch_bounds__(256) void decomp_k(const float* __restrict__ S, u16* __restrict__ X2B){
  int b = blockIdx.y, lc = blockIdx.x, d = threadIdx.x;
  const float* s = S + (size_t)b*L_SEQ*256;
  int l0 = lc*128;
  float w = 0.f;
  for (int j=-12;j<=12;j++){
    int g = l0+j; if (g < 0) g = 0; if (g > L_SEQ-1) g = L_SEQ-1;
    w += s[(size_t)g*256+d];
  }
  for (int l = l0; l < l0+128; l++){
    float c = s[(size_t)l*256+d];
    store_pair(c - w*(1.f/25.f), (size_t)b*L_SEQ + l, d, X2B);
    int ga = l+13; if (ga > L_SEQ-1) ga = L_SEQ-1;
    int gb = l-12; if (gb < 0) gb = 0;
    w += s[(size_t)ga*256+d] - s[(size_t)gb*256+d];
  }
}

// ---------- fused final LN + column (seq) partial reduce ----------
__global__ __launch_bounds__(256) void lncr_k(const u16* __restrict__ X2B, const float* __restrict__ LW,
                                              const float* __restrict__ LB, float* __restrict__ RS,
                                              float* __restrict__ RM){
  int b = blockIdx.y, lc = blockIdx.x;
  int tid = threadIdx.x, wv = tid>>6, l_ = tid&63;
  f32x4 lw = *(const f32x4*)(LW + l_*4);
  f32x4 lb = *(const f32x4*)(LB + l_*4);
  float cs[4] = {0,0,0,0};
  float cm[4] = {-3.4e38f,-3.4e38f,-3.4e38f,-3.4e38f};
  size_t tok0 = (size_t)b*L_SEQ + lc*128 + wv*32;
  for (int it = 0; it < 32; it++){
    const u16* xr = X2B + (tok0+it)*512 + l_*4;
    u16x4 hi = *(const u16x4*)xr;
    u16x4 lo = *(const u16x4*)(xr+256);
    float v[4]; float s=0.f, ss=0.f;
    #pragma unroll
    for (int j=0;j<4;j++){ v[j] = bf2f(hi[j]) + bf2f(lo[j]); s += v[j]; ss += v[j]*v[j]; }
    #pragma unroll
    for (int o=32;o>0;o>>=1){ s += __shfl_xor(s,o); ss += __shfl_xor(ss,o); }
    float mean = s*(1.f/256.f);
    float var = ss*(1.f/256.f) - mean*mean;
    float rstd = rsqrtf(var + 1e-5f);
    #pragma unroll
    for (int j=0;j<4;j++){
      float xh = (v[j]-mean)*rstd*lw[j] + lb[j];
      cs[j] += xh; cm[j] = fmaxf(cm[j], xh);
    }
  }
  __shared__ float S[4][256];
  __shared__ float M[4][256];
  #pragma unroll
  for (int j=0;j<4;j++){ S[wv][l_*4+j] = cs[j]; M[wv][l_*4+j] = cm[j]; }
  __syncthreads();
  float s4 = S[0][tid]+S[1][tid]+S[2][tid]+S[3][tid];
  float m4 = fmaxf(fmaxf(M[0][tid],M[1][tid]), fmaxf(M[2][tid],M[3][tid]));
  RS[((size_t)b*12+lc)*256+tid] = s4;
  RM[((size_t)b*12+lc)*256+tid] = m4;
}

// ---------- combine partials, gelu features, 176-proj ----------
__global__ __launch_bounds__(256) void final_k(const float* __restrict__ RS, const float* __restrict__ RM,
                                               const float* __restrict__ PW, const float* __restrict__ PB,
                                               float* __restrict__ OUT){
  __shared__ float feat[256];
  int b = blockIdx.x, tid = threadIdx.x;
  float s = 0.f, m = -3.4e38f;
  for (int c=0;c<12;c++){
    s += RS[((size_t)b*12+c)*256+tid];
    m = fmaxf(m, RM[((size_t)b*12+c)*256+tid]);
  }
  float mu = s*(1.f/1536.f);
  feat[tid] = gelu_f(m - mu);
  __syncthreads();
  if (tid < 176){
    float acc = PB[tid];
    for (int d=0; d<256; d++) acc += feat[d]*PW[(size_t)tid*512 + 256 + d];
    OUT[(size_t)b*176 + tid] = acc;
  }
}

// ================= host launch =================
extern "C" void kernel_launch(void* const* d_in, const int* in_sizes, int n_in,
                              void* d_out, int out_size, void* d_ws, size_t ws_size,
                              hipStream_t stream){
  const float* x_enc=(const float*)d_in[0];
  const float* emb_w=(const float*)d_in[1];
  const float* Wq=(const float*)d_in[2];  const float* bq=(const float*)d_in[3];
  const float* Wk=(const float*)d_in[4];  const float* bk=(const float*)d_in[5];
  const float* Wv=(const float*)d_in[6];  const float* bv=(const float*)d_in[7];
  const float* Wo=(const float*)d_in[8];  const float* bo=(const float*)d_in[9];
  const float* Wc1=(const float*)d_in[10]; const float* bc1=(const float*)d_in[11];
  const float* Wc2=(const float*)d_in[12]; const float* bc2=(const float*)d_in[13];
  const float* ln_w=(const float*)d_in[14]; const float* ln_b=(const float*)d_in[15];
  const float* pw=(const float*)d_in[16];  const float* pb=(const float*)d_in[17];
  (void)in_sizes; (void)n_in; (void)out_size;

  // adaptive batch-grouping so workspace fits ws_size
  int G = 1;
  while (G < 8){
    size_t need = (size_t)40*1024*1024 + (7ull*(size_t)(98304/G)*1024ull)/2;
    if (need <= ws_size) break;
    G *= 2;
  }
  const int NBG = 64 / G;            // batches per group
  const int NT  = NBG * L_SEQ;       // tokens per group

  char* ws = (char*)d_ws;
  size_t off = 0;
  auto alloc = [&](size_t bytes)->void*{
    void* p = ws + off; off += (bytes + 255) & ~(size_t)255; return p;
  };
  u16* W4QK = (u16*)alloc((size_t)2*512*1024*2);   // per layer: [Wq4;Wk4]
  u16* WVb  = (u16*)alloc((size_t)2*256*256*2);
  u16* WOb  = (u16*)alloc((size_t)2*256*256*2);
  u16* WC1b = (u16*)alloc((size_t)2*1024*256*2);
  u16* WC2b = (u16*)alloc((size_t)2*256*1024*2);
  float* MCP = (float*)alloc((size_t)2*GRAM_PLANE*4);
  int*  CANDI=(int*)  alloc(64*16*4);
  float*CANDV=(float*)alloc(64*16*4);
  int*  NEEDEX=(int*) alloc(64*4);
  int*  DLY = (int*)  alloc(64*8*4);
  float*WGT = (float*)alloc(64*8*4);
  float*RS  = (float*)alloc((size_t)64*12*256*4);
  float*RM  = (float*)alloc((size_t)64*12*256*4);
  u16* X2B = (u16*)alloc((size_t)NT*512*2);   // master activation: bf16 hi/lo pairs
  u16* Q2  = (u16*)alloc((size_t)NT*512*2);   // fp16 hi/lo pairs; aliased by AGG/HH
  u16* K2  = (u16*)alloc((size_t)NT*512*2);   // fp16 hi/lo pairs; aliased by SUM (f32)
  u16* V2  = (u16*)alloc((size_t)NT*256*2);   // bf16

  float* SUM = (float*)K2;
  u16*   AGG = Q2;
  u16*   HH  = Q2;

  // weight prep (once per call)
  for (int l = 0; l < 2; l++){
    w4b_k<<<256,256,0,stream>>>(Wq + (size_t)l*65536, W4QK + ((size_t)l*512+  0)*1024, 65536);
    w4b_k<<<256,256,0,stream>>>(Wk + (size_t)l*65536, W4QK + ((size_t)l*512+256)*1024, 65536);
  }
  castb_k<<<512,256,0,stream>>>(Wv, WVb, 2*256*256);
  castb_k<<<512,256,0,stream>>>(Wo, WOb, 2*256*256);
  castb_k<<<2048,256,0,stream>>>(Wc1, WC1b, 2*1024*256);
  castb_k<<<2048,256,0,stream>>>(Wc2, WC2b, 2*256*1024);

  for (int g = 0; g < G; g++){
    const float* xe = x_enc + (size_t)g*NBG*L_SEQ*7;
    float* outg = (float*)d_out + (size_t)g*NBG*176;

    embed_k<<<NT/64,256,0,stream>>>(xe, emb_w, X2B);

    for (int l = 0; l < 2; l++){
      // merged Q/K projections (split-bf16 K=1024), V separate at K=256
      gemmqk_k<<<dim3(NT/128,4),256,0,stream>>>(X2B, W4QK+(size_t)l*512*1024,
                                                bq+l*256, bk+l*256, Q2, K2);
      gemm_k<0,false><<<dim3(NT/128,2),256,0,stream>>>(X2B,512, WVb+(size_t)l*65536,256, bv+l*256, V2, 256, nullptr, 256);
      // mean correlation via banded circular gram (fp16 stage-1), jt-split x2
      gram_k<<<NBG*16,256,0,stream>>>(Q2, K2, MCP);
      // top-16 + provisional selection; flag ambiguous batches
      topk_k<<<NBG,256,0,stream>>>(MCP, CANDI, NEEDEX, DLY, WGT);
      // exact recompute only for flagged batches (typically none)
      recompute3_k<<<NBG*16,256,0,stream>>>(Q2, K2, CANDI, NEEDEX, CANDV);
      select7_k<<<NBG,64,0,stream>>>(CANDI, CANDV, NEEDEX, DLY, WGT);
      // weighted circular-delay aggregation (AGG aliases Q2)
      agg_k<<<NT/8,256,0,stream>>>(V2, DLY, WGT, AGG);
      // Wo + residual -> SUM (f32, aliases K2)
      gemm_k<2,false><<<dim3(NT/128,2),256,0,stream>>>(AGG,256, WOb+(size_t)l*65536,256, bo+l*256, SUM, 256, X2B, 256);
      decomp_k<<<dim3(12,NBG),256,0,stream>>>(SUM, X2B);
      // FFN in 2 M-chunks (HH aliases full Q2 region)
      for (int c = 0; c < 2; c++){
        const u16* Ac = X2B + (size_t)c*(NT/2)*512;
        gemm_k<1,false><<<dim3(NT/256,8),256,0,stream>>>(Ac,512, WC1b+(size_t)l*262144,256, bc1+l*1024, HH, 1024, nullptr, 256);
        gemm_k<2,false><<<dim3(NT/256,2),256,0,stream>>>(HH,1024, WC2b+(size_t)l*262144,1024, bc2+l*256,
                                                         SUM+(size_t)c*(NT/2)*256, 256, X2B+(size_t)c*(NT/2)*512, 1024);
      }
      decomp_k<<<dim3(12,NBG),256,0,stream>>>(SUM, X2B);
    }

    lncr_k<<<dim3(12,NBG),256,0,stream>>>(X2B, ln_w, ln_b, RS, RM);
    final_k<<<NBG,256,0,stream>>>(RS, RM, pw, pb, outg);
  }
}